// Round 12
// baseline (1298.575 us; speedup 1.0000x reference)
//
#include <hip/hip_runtime.h>
#include <math.h>

#define TT 2048
#define HH 64
#define NE 4       // batch elems per block
#define NBLK 128   // 512 / NE
#define NTHR 1024  // 16 waves

typedef _Float16 half8 __attribute__((ext_vector_type(8)));
typedef float f32x4 __attribute__((ext_vector_type(4)));

__device__ __forceinline__ float sigmoid_fast(float x) {
    float e = __expf(-x);
    return __builtin_amdgcn_rcpf(1.0f + e);
}
__device__ __forceinline__ float tanh_fast(float x) {
    float e = __expf(-2.0f * x);
    return fmaf(2.0f, __builtin_amdgcn_rcpf(1.0f + e), -1.0f);
}

// Round 12: round-11 2-phase structure, but 16 waves (4/SIMD) with a fully
// symmetric job split: wave w=(g=w>>2, j=w&3) computes C-tile (g,j) for BOTH
// layers: 2 MFMAs (Whh0) + 4 MFMAs (Wih1+Whh1) = 6/wave (was 12). Round-11
// counters: ~45% stall at 2 waves/SIMD (per-CU VALU 32% / MFMA 26%), chain =
// LDS latency -> MFMA latency -> 2 barrier drains. More waves + shorter
// phases fill the stall. Phase-2 (lanes<512, 1 unit-elem, 10 trans) and all
// arithmetic order identical to round 11 -> absmax should be bit-identical.
__global__ __launch_bounds__(NTHR) __attribute__((amdgpu_waves_per_eu(4, 4)))
void lstm_mfma2_kernel(const float* __restrict__ x,      // [B,T]
                       const float* __restrict__ w_ih0,  // [256,1]
                       const float* __restrict__ w_hh0,  // [256,64]
                       const float* __restrict__ b_ih0,  // [256]
                       const float* __restrict__ b_hh0,  // [256]
                       const float* __restrict__ w_ih1,  // [256,64]
                       const float* __restrict__ w_hh1,  // [256,64]
                       const float* __restrict__ b_ih1,  // [256]
                       const float* __restrict__ b_hh1,  // [256]
                       const float* __restrict__ w1, const float* __restrict__ b1,
                       const float* __restrict__ w2, const float* __restrict__ b2,
                       const float* __restrict__ w3, const float* __restrict__ b3,
                       float* __restrict__ out)          // [B,10]
{
    const int tid = threadIdx.x;
    const int wv  = tid >> 6;        // wave 0..15
    const int l   = tid & 63;
    const int e16 = l & 15;          // MFMA col (elem; valid < NE)
    const int kg  = l >> 4;          // k-group / C row-quad
    const int gw  = wv >> 2;         // owned gate tile
    const int jw  = wv & 3;          // owned row group
    const int bA  = blockIdx.x * NE;

    __shared__ __align__(16) float xs[(TT + 1) * (NE + 1)];    // [t][5] pad
    __shared__ __align__(16) float glds[2][4][NE][72];         // [L][g][e][u pad]
    __shared__ __align__(16) _Float16 h0lds[16 * 64];          // [e16][u] swizzled
    __shared__ __align__(16) _Float16 h1lds[16 * 64];
    __shared__ float cls1[NE][HH];
    __shared__ float cls2[NE][32];

    // zero h (rows 4..15 are garbage cols, still readable)
    for (int i = tid; i < 16 * 64; i += NTHR) {
        h0lds[i] = (_Float16)0.0f;
        h1lds[i] = (_Float16)0.0f;
    }
    // stage x: xs[t*5+e] (stride-5 -> conflict-free), coalesced global reads
    for (int i = tid; i < NE * TT; i += NTHR) {
        const int e = i >> 11, t = i & (TT - 1);
        xs[t * (NE + 1) + e] = x[(size_t)(bA + e) * TT + t];
    }
    if (tid < NE + 1) xs[TT * (NE + 1) + tid] = 0.0f;   // pad row t=TT

    // ---- weight A-frags (fp16): 6 half8 = 24 VGPR per lane ----
    // wf[0..1]=Whh0(gw,jw), wf[2..3]=Wih1(gw,jw), wf[4..5]=Whh1(gw,jw)
    half8 wf[6];
    {
        auto frag = [&](const float* M, int kc) {
            const int row = gw * 64 + 16 * jw + e16;   // A-frag row = l&15
            half8 v;
            #pragma unroll
            for (int i = 0; i < 8; ++i) v[i] = (_Float16)M[row * HH + kc * 32 + kg * 8 + i];
            return v;
        };
        wf[0] = frag(w_hh0, 0); wf[1] = frag(w_hh0, 1);
        wf[2] = frag(w_ih1, 0); wf[3] = frag(w_ih1, 1);
        wf[4] = frag(w_hh1, 0); wf[5] = frag(w_hh1, 1);
    }

    // ---- activation-phase identity (lanes < 512): (L, unit au, elem ae) ----
    const int L  = tid >> 8;         // 0..1 for tid<512
    const int au = (tid >> 2) & 63;
    const int ae = tid & 3;
    float bi[4], wxr[4];
    {
        const float* bihp = (L & 1) ? b_ih1 : b_ih0;
        const float* bhhp = (L & 1) ? b_hh1 : b_hh0;
        #pragma unroll
        for (int g = 0; g < 4; ++g) {
            bi[g]  = bihp[g * 64 + au] + bhhp[g * 64 + au];
            wxr[g] = (L & 1) ? 0.0f : w_ih0[g * 64 + au];
        }
    }
    // pin (rounds 1-4 lesson: allocator rematerializes weight loads otherwise)
    #pragma unroll
    for (int i = 0; i < 6; ++i) asm volatile("" : "+v"(wf[i]));
    #pragma unroll
    for (int g = 0; g < 4; ++g) {
        asm volatile("" : "+v"(bi[g]));
        asm volatile("" : "+v"(wxr[g]));
    }

    float c = 0.0f;                                   // lane's cell state
    _Float16* const hW = (L & 1) ? h1lds : h0lds;     // act write target
    const int hwb = ae * 128 + ((2 * au) ^ (ae << 4));   // byte, swizzled

    const int swz16 = (e16 & 7) << 4;
    const int hro0 = e16 * 128 + ((16 * kg) ^ swz16);        // k-chunk 0
    const int hro1 = e16 * 128 + ((64 + 16 * kg) ^ swz16);   // k-chunk 1
    const f32x4 z4 = {0.0f, 0.0f, 0.0f, 0.0f};

    __syncthreads();

    for (int t = 0; t <= TT; ++t) {
        // ---- phase 1: MFMA gates0(t), gates1(t-1) -> glds (raw, no bias) ----
        {
            half8 h0f0 = *(const half8*)((const char*)h0lds + hro0);
            half8 h0f1 = *(const half8*)((const char*)h0lds + hro1);
            half8 h1f0 = *(const half8*)((const char*)h1lds + hro0);
            half8 h1f1 = *(const half8*)((const char*)h1lds + hro1);
            f32x4 a0, a1;
            a0 = __builtin_amdgcn_mfma_f32_16x16x32_f16(wf[0], h0f0, z4, 0, 0, 0);
            a0 = __builtin_amdgcn_mfma_f32_16x16x32_f16(wf[1], h0f1, a0, 0, 0, 0);
            a1 = __builtin_amdgcn_mfma_f32_16x16x32_f16(wf[2], h0f0, z4, 0, 0, 0);
            a1 = __builtin_amdgcn_mfma_f32_16x16x32_f16(wf[3], h0f1, a1, 0, 0, 0);
            a1 = __builtin_amdgcn_mfma_f32_16x16x32_f16(wf[4], h1f0, a1, 0, 0, 0);
            a1 = __builtin_amdgcn_mfma_f32_16x16x32_f16(wf[5], h1f1, a1, 0, 0, 0);
            if (e16 < NE) {
                const int u0 = 16 * jw + 4 * kg;
                *(f32x4*)&glds[0][gw][e16][u0] = a0;
                *(f32x4*)&glds[1][gw][e16][u0] = a1;
            }
        }
        __syncthreads();

        // ---- phase 2: activation, 1 unit-elem per lane (lanes < 512) ----
        if (tid < 512) {
            float z0 = glds[L][0][ae][au];
            float z1 = glds[L][1][ae][au];
            float z2 = glds[L][2][ae][au];
            float z3 = glds[L][3][ae][au];
            const float xt = xs[t * (NE + 1) + ae];
            z0 += fmaf(wxr[0], xt, bi[0]);
            z1 += fmaf(wxr[1], xt, bi[1]);
            z2 += fmaf(wxr[2], xt, bi[2]);
            z3 += fmaf(wxr[3], xt, bi[3]);
            float gi = sigmoid_fast(z0);
            float gf = sigmoid_fast(z1);
            float gg = tanh_fast(z2);
            float go = sigmoid_fast(z3);
            c = fmaf(gf, c, gi * gg);
            float h = go * tanh_fast(c);
            if (L && t == 0) { c = 0.0f; h = 0.0f; }   // enforce h1(-1)=0
            *(_Float16*)((char*)hW + hwb) = (_Float16)h;
        }
        __syncthreads();
    }
    // h1lds now holds h1(TT-1) = h_last

    // ---- classifier head: wave wv<4 handles elem wv ----
    if (wv < 4) {
        float a = b1[l];
        #pragma unroll 8
        for (int k = 0; k < HH; ++k) {
            const float hk = (float)*(const _Float16*)((const char*)h1lds
                                + wv * 128 + ((2 * k) ^ (wv << 4)));
            a = fmaf(w1[l * HH + k], hk, a);
        }
        cls1[wv][l] = fmaxf(a, 0.0f);
    }
    __syncthreads();
    if (wv < 4 && l < 32) {
        float a = b2[l];
        #pragma unroll 8
        for (int k = 0; k < HH; ++k) a = fmaf(w2[l * HH + k], cls1[wv][k], a);
        cls2[wv][l] = fmaxf(a, 0.0f);
    }
    __syncthreads();
    if (wv < 4 && l < 10) {
        float a = b3[l];
        #pragma unroll
        for (int k = 0; k < 32; ++k) a = fmaf(w3[l * 32 + k], cls2[wv][k], a);
        out[(size_t)(bA + wv) * 10 + l] = a;
    }
}

extern "C" void kernel_launch(void* const* d_in, const int* in_sizes, int n_in,
                              void* d_out, int out_size, void* d_ws, size_t ws_size,
                              hipStream_t stream) {
    const float* x     = (const float*)d_in[0];
    const float* w_ih0 = (const float*)d_in[1];
    const float* w_hh0 = (const float*)d_in[2];
    const float* b_ih0 = (const float*)d_in[3];
    const float* b_hh0 = (const float*)d_in[4];
    const float* w_ih1 = (const float*)d_in[5];
    const float* w_hh1 = (const float*)d_in[6];
    const float* b_ih1 = (const float*)d_in[7];
    const float* b_hh1 = (const float*)d_in[8];
    const float* w1    = (const float*)d_in[9];
    const float* b1    = (const float*)d_in[10];
    const float* w2    = (const float*)d_in[11];
    const float* b2    = (const float*)d_in[12];
    const float* w3    = (const float*)d_in[13];
    const float* b3    = (const float*)d_in[14];
    float* out = (float*)d_out;

    lstm_mfma2_kernel<<<NBLK, NTHR, 0, stream>>>(x, w_ih0, w_hh0, b_ih0, b_hh0,
                                                 w_ih1, w_hh1, b_ih1, b_hh1,
                                                 w1, b1, w2, b2, w3, b3, out);
}